// Round 1
// baseline (583.556 us; speedup 1.0000x reference)
//
#include <hip/hip_runtime.h>
#include <hip/hip_bf16.h>
#include <math.h>

// Problem constants
#define TSEQ 2048
#define NBATCH 4
#define NTOK (TSEQ * NBATCH)   // 8192
#define DM 128
#define WIN 64
#define DFF 256
#define NQKV 384

// ---------------- in_proj (Linear->ReLU->Linear) + sinusoidal PE ----------------
// block = 128 threads, each block handles ROWS consecutive tokens.
template<int ROWS>
__global__ void k_inproj(const float* __restrict__ E, const float* __restrict__ rho,
                         const float* __restrict__ W1, const float* __restrict__ b1,
                         const float* __restrict__ W2, const float* __restrict__ b2,
                         float* __restrict__ h) {
    const int row0 = blockIdx.x * ROWS;
    const int tid = threadIdx.x;  // 0..127
    __shared__ float x[ROWS][16];
    __shared__ float h1[ROWS][DM];

    for (int idx = tid; idx < ROWS * 16; idx += DM) {
        int r = idx >> 4, c = idx & 15;
        int tok = row0 + r;
        x[r][c] = (c < 8) ? E[(size_t)tok * 8 + c] : rho[(size_t)tok * 8 + (c - 8)];
    }
    __syncthreads();

    float acc[ROWS];
#pragma unroll
    for (int r = 0; r < ROWS; ++r) acc[r] = b1[tid];
    for (int k = 0; k < 16; ++k) {
        float w = W1[k * DM + tid];
#pragma unroll
        for (int r = 0; r < ROWS; ++r) acc[r] += x[r][k] * w;
    }
#pragma unroll
    for (int r = 0; r < ROWS; ++r) h1[r][tid] = fmaxf(acc[r], 0.f);
    __syncthreads();

#pragma unroll
    for (int r = 0; r < ROWS; ++r) acc[r] = b2[tid];
    for (int k = 0; k < DM; ++k) {
        float w = W2[k * DM + tid];
#pragma unroll
        for (int r = 0; r < ROWS; ++r) acc[r] += h1[r][k] * w;
    }

    // positional encoding: channel c even -> sin(t*div[c/2]), odd -> cos
    const float c0 = -0.14391156831212787f;  // -ln(10000)/64
    float dv = __expf(c0 * (float)(tid >> 1));
#pragma unroll
    for (int r = 0; r < ROWS; ++r) {
        int tok = row0 + r;
        int t = tok & (TSEQ - 1);
        float ang = (float)t * dv;
        float pe = (tid & 1) ? cosf(ang) : sinf(ang);
        h[(size_t)tok * DM + tid] = acc[r] + pe;
    }
}

// ---------------- generic row-block GEMM: C[M,N] = act(A[M,K] @ W[K,N] + bias) ----------------
// block = N threads, each block does ROWS consecutive rows (A rows staged in LDS).
template<int K, int N, int ROWS, bool RELU>
__global__ void k_gemm(const float* __restrict__ A, const float* __restrict__ W,
                       const float* __restrict__ bias, float* __restrict__ C) {
    const int row0 = blockIdx.x * ROWS;
    const int tid = threadIdx.x;  // 0..N-1
    __shared__ float a[ROWS * K];
    for (int idx = tid; idx < ROWS * K; idx += N)
        a[idx] = A[(size_t)row0 * K + idx];
    __syncthreads();

    float acc[ROWS];
#pragma unroll
    for (int r = 0; r < ROWS; ++r) acc[r] = bias[tid];
    for (int k = 0; k < K; ++k) {
        float w = W[(size_t)k * N + tid];
#pragma unroll
        for (int r = 0; r < ROWS; ++r) acc[r] += a[r * K + k] * w;
    }
#pragma unroll
    for (int r = 0; r < ROWS; ++r) {
        float v = acc[r];
        C[(size_t)(row0 + r) * N + tid] = RELU ? fmaxf(v, 0.f) : v;
    }
}

// ---------------- banded causal attention, window=64, 4 heads of dim 32 ----------------
// One block (256 threads = 4 waves) per token; wave w handles head w.
// qkv layout per token: [0:128)=q, [128:256)=k, [256:384)=v, head h occupies [h*32,(h+1)*32).
__global__ void k_attn(const float* __restrict__ qkv, float* __restrict__ o) {
    const int tok = blockIdx.x;
    const int t = tok & (TSEQ - 1);
    const int b = tok >> 11;
    const int tid = threadIdx.x;  // 0..255
    const int head = tid >> 6;
    const int lane = tid & 63;
    __shared__ float p[4][WIN];

    const int j = t - (WIN - 1) + lane;  // key position, lane 63 -> j == t
    float score = -1e30f;
    if (j >= 0) {
        const float* q = qkv + (size_t)tok * NQKV + head * 32;
        const float* kk = qkv + ((size_t)(b * TSEQ + j)) * NQKV + 128 + head * 32;
        float s = 0.f;
#pragma unroll
        for (int d = 0; d < 32; ++d) s += q[d] * kk[d];
        score = s * 0.17677669529663687f;  // 1/sqrt(32)
    }
    // 64-lane softmax
    float m = score;
#pragma unroll
    for (int off = 32; off; off >>= 1) m = fmaxf(m, __shfl_xor(m, off));
    float e = (j >= 0) ? __expf(score - m) : 0.f;
    float sum = e;
#pragma unroll
    for (int off = 32; off; off >>= 1) sum += __shfl_xor(sum, off);
    p[head][lane] = e / sum;
    __syncthreads();

    // PV: threads 0..127 compute the 128 output channels (head = tid/32, d = tid%32)
    if (tid < DM) {
        const int h2 = tid >> 5, d = tid & 31;
        const int j0 = t - (WIN - 1);
        float acc = 0.f;
#pragma unroll 8
        for (int jj = 0; jj < WIN; ++jj) {
            int jr = j0 + jj;
            if (jr >= 0)
                acc += p[h2][jj] * qkv[((size_t)(b * TSEQ + jr)) * NQKV + 256 + h2 * 32 + d];
        }
        o[(size_t)tok * DM + tid] = acc;
    }
}

// ---------------- projection + residual + LayerNorm ----------------
// h = LN(h + A @ W + bias); block = 128 threads, ROWS tokens per block.
template<int K, int ROWS>
__global__ void k_proj_res_ln(const float* __restrict__ A, const float* __restrict__ W,
                              const float* __restrict__ bias,
                              const float* __restrict__ g, const float* __restrict__ be,
                              float* __restrict__ h) {
    const int row0 = blockIdx.x * ROWS;
    const int tid = threadIdx.x;  // 0..127
    const int wv = tid >> 6, ln = tid & 63;
    __shared__ float a[ROWS * K];
    __shared__ float rsum[2][ROWS], rsq[2][ROWS];

    for (int idx = tid; idx < ROWS * K; idx += DM)
        a[idx] = A[(size_t)row0 * K + idx];
    __syncthreads();

    float acc[ROWS];
#pragma unroll
    for (int r = 0; r < ROWS; ++r)
        acc[r] = bias[tid] + h[(size_t)(row0 + r) * DM + tid];
    for (int k = 0; k < K; ++k) {
        float w = W[(size_t)k * DM + tid];
#pragma unroll
        for (int r = 0; r < ROWS; ++r) acc[r] += a[r * K + k] * w;
    }

    // per-row LayerNorm over 128 channels (2 waves -> shfl reduce + LDS combine)
#pragma unroll
    for (int r = 0; r < ROWS; ++r) {
        float s = acc[r], s2 = acc[r] * acc[r];
#pragma unroll
        for (int off = 32; off; off >>= 1) {
            s  += __shfl_xor(s,  off);
            s2 += __shfl_xor(s2, off);
        }
        if (ln == 0) { rsum[wv][r] = s; rsq[wv][r] = s2; }
    }
    __syncthreads();
    float gg = g[tid], bb = be[tid];
#pragma unroll
    for (int r = 0; r < ROWS; ++r) {
        float mean = (rsum[0][r] + rsum[1][r]) * (1.f / DM);
        float var  = (rsq[0][r] + rsq[1][r]) * (1.f / DM) - mean * mean;
        h[(size_t)(row0 + r) * DM + tid] = (acc[r] - mean) * rsqrtf(var + 1e-5f) * gg + bb;
    }
}

// ---------------- output head: (NTOK,128) @ (128,8) + b ----------------
__global__ void k_head(const float* __restrict__ h, const float* __restrict__ W,
                       const float* __restrict__ bias, float* __restrict__ out) {
    const int tok = blockIdx.x * blockDim.x + threadIdx.x;
    if (tok >= NTOK) return;
    float acc[8];
#pragma unroll
    for (int r = 0; r < 8; ++r) acc[r] = bias[r];
    for (int k = 0; k < DM; ++k) {
        float hv = h[(size_t)tok * DM + k];
#pragma unroll
        for (int r = 0; r < 8; ++r) acc[r] += hv * W[k * 8 + r];
    }
#pragma unroll
    for (int r = 0; r < 8; ++r) out[(size_t)tok * 8 + r] = acc[r];
}

extern "C" void kernel_launch(void* const* d_in, const int* in_sizes, int n_in,
                              void* d_out, int out_size, void* d_ws, size_t ws_size,
                              hipStream_t stream) {
    const float* E     = (const float*)d_in[0];
    const float* rho   = (const float*)d_in[1];
    const float* W_in1 = (const float*)d_in[2];
    const float* b_in1 = (const float*)d_in[3];
    const float* W_in2 = (const float*)d_in[4];
    const float* b_in2 = (const float*)d_in[5];
    const float* Wqkv  = (const float*)d_in[6];
    const float* bqkv  = (const float*)d_in[7];
    const float* Wo    = (const float*)d_in[8];
    const float* bo    = (const float*)d_in[9];
    const float* ln1g  = (const float*)d_in[10];
    const float* ln1b  = (const float*)d_in[11];
    const float* Wff1  = (const float*)d_in[12];
    const float* bff1  = (const float*)d_in[13];
    const float* Wff2  = (const float*)d_in[14];
    const float* bff2  = (const float*)d_in[15];
    const float* ln2g  = (const float*)d_in[16];
    const float* ln2b  = (const float*)d_in[17];
    const float* Whead = (const float*)d_in[18];
    const float* bhead = (const float*)d_in[19];
    float* out = (float*)d_out;

    // workspace: h (4MB) | buf1 qkv/ff1 (12MB) | o (4MB)  => 20MB total
    float* h    = (float*)d_ws;
    float* buf1 = (float*)((char*)d_ws + (size_t)4 * 1024 * 1024);
    float* obuf = (float*)((char*)d_ws + (size_t)16 * 1024 * 1024);

    constexpr int ROWS = 8;
    k_inproj<ROWS><<<NTOK / ROWS, DM, 0, stream>>>(E, rho, W_in1, b_in1, W_in2, b_in2, h);
    for (int l = 0; l < 3; ++l) {
        k_gemm<DM, NQKV, ROWS, false><<<NTOK / ROWS, NQKV, 0, stream>>>(
            h, Wqkv + (size_t)l * DM * NQKV, bqkv + l * NQKV, buf1);
        k_attn<<<NTOK, 256, 0, stream>>>(buf1, obuf);
        k_proj_res_ln<DM, ROWS><<<NTOK / ROWS, DM, 0, stream>>>(
            obuf, Wo + (size_t)l * DM * DM, bo + l * DM, ln1g + l * DM, ln1b + l * DM, h);
        k_gemm<DM, DFF, ROWS, true><<<NTOK / ROWS, DFF, 0, stream>>>(
            h, Wff1 + (size_t)l * DM * DFF, bff1 + l * DFF, buf1);
        k_proj_res_ln<DFF, ROWS><<<NTOK / ROWS, DM, 0, stream>>>(
            buf1, Wff2 + (size_t)l * DFF * DM, bff2 + l * DM, ln2g + l * DM, ln2b + l * DM, h);
    }
    k_head<<<NTOK / 256, 256, 0, stream>>>(h, Whead, bhead, out);
}

// Round 6
// 326.079 us; speedup vs baseline: 1.7896x; 1.7896x over previous
//
#include <hip/hip_runtime.h>
#include <hip/hip_bf16.h>
#include <math.h>

// Problem constants
#define TSEQ 2048
#define NBATCH 4
#define NTOK (TSEQ * NBATCH)   // 8192
#define DM 128
#define WIN 64
#define DFF 256
#define NQKV 384
#define QT 64                  // query tile for attention

typedef __attribute__((ext_vector_type(8))) short bf16x8;
typedef __attribute__((ext_vector_type(4))) float f32x4;

__device__ __forceinline__ unsigned short f2bf(float f) {
    union { float f; unsigned int u; } v; v.f = f;
    unsigned int r = v.u + 0x7fffu + ((v.u >> 16) & 1u);  // RNE
    return (unsigned short)(r >> 16);
}
__device__ __forceinline__ float bf2f_lo(unsigned int u) {
    union { unsigned int u; float f; } v; v.u = u << 16; return v.f;
}
__device__ __forceinline__ float bf2f_hi(unsigned int u) {
    union { unsigned int u; float f; } v; v.u = u & 0xffff0000u; return v.f;
}

// ---------------- weight convert + transpose to bf16: Wt[l][n][k] = W[l][k][n] ----------------
__global__ void k_wconv(const float* __restrict__ Wqkv, const float* __restrict__ Wo,
                        const float* __restrict__ Wff1, const float* __restrict__ Wff2,
                        unsigned short* __restrict__ wq, unsigned short* __restrict__ wo,
                        unsigned short* __restrict__ w1, unsigned short* __restrict__ w2) {
    int idx = blockIdx.x * 256 + threadIdx.x;
    const int s1 = 3 * 128 * 384, s2 = 3 * 128 * 128, s3 = 3 * 128 * 256, s4 = 3 * 256 * 128;
    if (idx < s1) {                       // K=128, N=384
        int l = idx / (384 * 128), rem = idx % (384 * 128);
        int n = rem / 128, k = rem % 128;
        wq[idx] = f2bf(Wqkv[(size_t)l * 128 * 384 + k * 384 + n]);
    } else if ((idx -= s1) < s2) {        // K=128, N=128
        int l = idx / (128 * 128), rem = idx % (128 * 128);
        int n = rem / 128, k = rem % 128;
        wo[idx] = f2bf(Wo[(size_t)l * 128 * 128 + k * 128 + n]);
    } else if ((idx -= s2) < s3) {        // K=128, N=256
        int l = idx / (256 * 128), rem = idx % (256 * 128);
        int n = rem / 128, k = rem % 128;
        w1[idx] = f2bf(Wff1[(size_t)l * 128 * 256 + k * 256 + n]);
    } else if ((idx -= s3) < s4) {        // K=256, N=128
        int l = idx / (128 * 256), rem = idx % (128 * 256);
        int n = rem / 256, k = rem % 256;
        w2[idx] = f2bf(Wff2[(size_t)l * 256 * 128 + k * 128 + n]);
    }
}

// ---------------- in_proj (Linear->ReLU->Linear) + sinusoidal PE ----------------
template<int ROWS>
__global__ void k_inproj(const float* __restrict__ E, const float* __restrict__ rho,
                         const float* __restrict__ W1, const float* __restrict__ b1,
                         const float* __restrict__ W2, const float* __restrict__ b2,
                         float* __restrict__ h, unsigned short* __restrict__ hbf) {
    const int row0 = blockIdx.x * ROWS;
    const int tid = threadIdx.x;  // 0..127
    __shared__ float x[ROWS][16];
    __shared__ float h1[ROWS][DM];

    for (int idx = tid; idx < ROWS * 16; idx += DM) {
        int r = idx >> 4, c = idx & 15;
        int tok = row0 + r;
        x[r][c] = (c < 8) ? E[(size_t)tok * 8 + c] : rho[(size_t)tok * 8 + (c - 8)];
    }
    __syncthreads();

    float acc[ROWS];
#pragma unroll
    for (int r = 0; r < ROWS; ++r) acc[r] = b1[tid];
    for (int k = 0; k < 16; ++k) {
        float w = W1[k * DM + tid];
#pragma unroll
        for (int r = 0; r < ROWS; ++r) acc[r] += x[r][k] * w;
    }
#pragma unroll
    for (int r = 0; r < ROWS; ++r) h1[r][tid] = fmaxf(acc[r], 0.f);
    __syncthreads();

#pragma unroll
    for (int r = 0; r < ROWS; ++r) acc[r] = b2[tid];
    for (int k = 0; k < DM; ++k) {
        float w = W2[k * DM + tid];
#pragma unroll
        for (int r = 0; r < ROWS; ++r) acc[r] += h1[r][k] * w;
    }

    const float c0 = -0.14391156831212787f;  // -ln(10000)/64
    float dv = __expf(c0 * (float)(tid >> 1));
#pragma unroll
    for (int r = 0; r < ROWS; ++r) {
        int tok = row0 + r;
        int t = tok & (TSEQ - 1);
        float ang = (float)t * dv;
        float pe = (tid & 1) ? cosf(ang) : sinf(ang);
        float v = acc[r] + pe;
        h[(size_t)tok * DM + tid] = v;
        hbf[(size_t)tok * DM + tid] = f2bf(v);
    }
}

// ---------------- MFMA GEMM: C[M,N] = act(Abf[M,K] @ Wt[N,K]^T + bias) ----------------
// 64x64 tile, 4 waves; wave w does rows w*16..w*16+15 of the tile, 4 col-subtiles of 16.
// mfma_f32_16x16x32_bf16: A row=lane&15, k=8*(lane>>4)+j ; B col=lane&15, same k ;
// C/D col=lane&15, row=(lane>>4)*4+reg (HW-verified m89).
template<int K, int N, bool RELU, bool OUTBF16>
__global__ __launch_bounds__(256) void k_gemm_mfma(
        const unsigned short* __restrict__ A,   // M x K bf16 row-major
        const unsigned short* __restrict__ Wt,  // N x K bf16 row-major (transposed weight)
        const float* __restrict__ bias,         // N
        void* __restrict__ Cout) {              // M x N (fp32 or bf16)
    const int bm0 = blockIdx.x * 64;
    const int bn0 = blockIdx.y * 64;
    const int w = threadIdx.x >> 6;
    const int l = threadIdx.x & 63;
    const int lr = l & 15;
    const int lk = l >> 4;
    const int arow = bm0 + w * 16 + lr;

    bf16x8 aF[K / 32];
    const unsigned short* ap = A + (size_t)arow * K + lk * 8;
#pragma unroll
    for (int ks = 0; ks < K / 32; ++ks)
        aF[ks] = *(const bf16x8*)(ap + ks * 32);

    f32x4 acc[4];
#pragma unroll
    for (int nt = 0; nt < 4; ++nt) {
        float b = bias[bn0 + nt * 16 + lr];
        acc[nt][0] = b; acc[nt][1] = b; acc[nt][2] = b; acc[nt][3] = b;
    }

#pragma unroll
    for (int ks = 0; ks < K / 32; ++ks) {
#pragma unroll
        for (int nt = 0; nt < 4; ++nt) {
            const unsigned short* bp = Wt + (size_t)(bn0 + nt * 16 + lr) * K + ks * 32 + lk * 8;
            bf16x8 bF = *(const bf16x8*)bp;
            acc[nt] = __builtin_amdgcn_mfma_f32_16x16x32_bf16(aF[ks], bF, acc[nt], 0, 0, 0);
        }
    }

#pragma unroll
    for (int nt = 0; nt < 4; ++nt) {
        int col = bn0 + nt * 16 + lr;
#pragma unroll
        for (int r = 0; r < 4; ++r) {
            int row = bm0 + w * 16 + lk * 4 + r;
            float v = acc[nt][r];
            if (RELU) v = fmaxf(v, 0.f);
            if (OUTBF16) ((unsigned short*)Cout)[(size_t)row * N + col] = f2bf(v);
            else ((float*)Cout)[(size_t)row * N + col] = v;
        }
    }
}

// ---------------- tiled banded attention (bf16 qkv in, bf16 o out) ----------------
__global__ void k_attn2(const unsigned short* __restrict__ qkv, unsigned short* __restrict__ o) {
    const int t0   = blockIdx.x * QT;
    const int head = blockIdx.y;
    const int b    = blockIdx.z;
    const int tid  = threadIdx.x;
    const int q    = tid >> 2;
    const int s    = tid & 3;

    __shared__ float kbuf[127][36];
    __shared__ float vbuf[127][36];

    // stage K/V (tokens j = t0-63 .. t0+63) as fp32 in LDS; zero-fill j<0
    for (int idx = tid; idx < 127 * 4; idx += 256) {
        int kb = idx >> 2, c = idx & 3;  // c: 8-dim group
        int j = t0 - 63 + kb;
        uint4 kv = make_uint4(0, 0, 0, 0), vv = make_uint4(0, 0, 0, 0);
        if (j >= 0) {
            const unsigned short* base = qkv + ((size_t)(b * TSEQ + j)) * NQKV + head * 32 + c * 8;
            kv = *(const uint4*)(base + 128);
            vv = *(const uint4*)(base + 256);
        }
        float* kd = &kbuf[kb][c * 8];
        float* vd = &vbuf[kb][c * 8];
        kd[0] = bf2f_lo(kv.x); kd[1] = bf2f_hi(kv.x); kd[2] = bf2f_lo(kv.y); kd[3] = bf2f_hi(kv.y);
        kd[4] = bf2f_lo(kv.z); kd[5] = bf2f_hi(kv.z); kd[6] = bf2f_lo(kv.w); kd[7] = bf2f_hi(kv.w);
        vd[0] = bf2f_lo(vv.x); vd[1] = bf2f_hi(vv.x); vd[2] = bf2f_lo(vv.y); vd[3] = bf2f_hi(vv.y);
        vd[4] = bf2f_lo(vv.z); vd[5] = bf2f_hi(vv.z); vd[6] = bf2f_lo(vv.w); vd[7] = bf2f_hi(vv.w);
    }

    // Q row into registers
    float qreg[32];
    {
        const unsigned short* qp = qkv + ((size_t)(b * TSEQ + t0 + q)) * NQKV + head * 32;
#pragma unroll
        for (int c = 0; c < 4; ++c) {
            uint4 u = *(const uint4*)(qp + c * 8);
            float* qd = &qreg[c * 8];
            qd[0] = bf2f_lo(u.x); qd[1] = bf2f_hi(u.x); qd[2] = bf2f_lo(u.y); qd[3] = bf2f_hi(u.y);
            qd[4] = bf2f_lo(u.z); qd[5] = bf2f_hi(u.z); qd[6] = bf2f_lo(u.w); qd[7] = bf2f_hi(u.w);
        }
    }
    __syncthreads();

    const float scale = 0.17677669529663687f;  // 1/sqrt(32)
    float sc[16];
#pragma unroll
    for (int kk = 0; kk < 16; ++kk) {
        int w = s + 4 * kk;
        int kb = q + w;
        float acc = 0.f;
#pragma unroll
        for (int d = 0; d < 32; ++d) acc += qreg[d] * kbuf[kb][d];
        int j = t0 + q - 63 + w;
        sc[kk] = (j >= 0) ? acc * scale : -1e30f;
    }

    float m = sc[0];
#pragma unroll
    for (int kk = 1; kk < 16; ++kk) m = fmaxf(m, sc[kk]);
    m = fmaxf(m, __shfl_xor(m, 1));
    m = fmaxf(m, __shfl_xor(m, 2));
    float sum = 0.f;
#pragma unroll
    for (int kk = 0; kk < 16; ++kk) { sc[kk] = __expf(sc[kk] - m); sum += sc[kk]; }
    sum += __shfl_xor(sum, 1);
    sum += __shfl_xor(sum, 2);
    const float inv = 1.f / sum;

    float acc[32];
#pragma unroll
    for (int d = 0; d < 32; ++d) acc[d] = 0.f;
#pragma unroll
    for (int kk = 0; kk < 16; ++kk) {
        float p = sc[kk] * inv;
        int kb = q + s + 4 * kk;
#pragma unroll
        for (int d = 0; d < 32; ++d) acc[d] += p * vbuf[kb][d];
    }
#pragma unroll
    for (int d = 0; d < 32; ++d) {
        acc[d] += __shfl_xor(acc[d], 1);
        acc[d] += __shfl_xor(acc[d], 2);
    }
    if (s == 0) {
        unsigned short* op = o + ((size_t)(b * TSEQ + t0 + q)) * DM + head * 32;
#pragma unroll
        for (int d = 0; d < 32; d += 2) {
            unsigned int u = ((unsigned int)f2bf(acc[d + 1]) << 16) | f2bf(acc[d]);
            *(unsigned int*)(op + d) = u;
        }
    }
}

// ---------------- residual + LayerNorm: h = LN(h + G); writes fp32 h and bf16 hbf ----------------
template<int ROWS>
__global__ void k_res_ln(const float* __restrict__ G,
                         const float* __restrict__ g, const float* __restrict__ be,
                         float* __restrict__ h, unsigned short* __restrict__ hbf) {
    const int row0 = blockIdx.x * ROWS;
    const int tid = threadIdx.x;  // 0..127
    const int wv = tid >> 6, ln = tid & 63;
    __shared__ float rsum[2][ROWS], rsq[2][ROWS];

    float acc[ROWS];
#pragma unroll
    for (int r = 0; r < ROWS; ++r)
        acc[r] = h[(size_t)(row0 + r) * DM + tid] + G[(size_t)(row0 + r) * DM + tid];

#pragma unroll
    for (int r = 0; r < ROWS; ++r) {
        float s = acc[r], s2 = acc[r] * acc[r];
#pragma unroll
        for (int off = 32; off; off >>= 1) {
            s  += __shfl_xor(s,  off);
            s2 += __shfl_xor(s2, off);
        }
        if (ln == 0) { rsum[wv][r] = s; rsq[wv][r] = s2; }
    }
    __syncthreads();
    float gg = g[tid], bb = be[tid];
#pragma unroll
    for (int r = 0; r < ROWS; ++r) {
        float mean = (rsum[0][r] + rsum[1][r]) * (1.f / DM);
        float var  = (rsq[0][r] + rsq[1][r]) * (1.f / DM) - mean * mean;
        float v = (acc[r] - mean) * rsqrtf(var + 1e-5f) * gg + bb;
        h[(size_t)(row0 + r) * DM + tid] = v;
        hbf[(size_t)(row0 + r) * DM + tid] = f2bf(v);
    }
}

// ---------------- output head: (NTOK,128) @ (128,8) + b ----------------
__global__ void k_head(const float* __restrict__ h, const float* __restrict__ W,
                       const float* __restrict__ bias, float* __restrict__ out) {
    const int tok = blockIdx.x * blockDim.x + threadIdx.x;
    if (tok >= NTOK) return;
    float acc[8];
#pragma unroll
    for (int r = 0; r < 8; ++r) acc[r] = bias[r];
    for (int k = 0; k < DM; ++k) {
        float hv = h[(size_t)tok * DM + k];
#pragma unroll
        for (int r = 0; r < 8; ++r) acc[r] += hv * W[k * 8 + r];
    }
#pragma unroll
    for (int r = 0; r < 8; ++r) out[(size_t)tok * 8 + r] = acc[r];
}

extern "C" void kernel_launch(void* const* d_in, const int* in_sizes, int n_in,
                              void* d_out, int out_size, void* d_ws, size_t ws_size,
                              hipStream_t stream) {
    const float* E     = (const float*)d_in[0];
    const float* rho   = (const float*)d_in[1];
    const float* W_in1 = (const float*)d_in[2];
    const float* b_in1 = (const float*)d_in[3];
    const float* W_in2 = (const float*)d_in[4];
    const float* b_in2 = (const float*)d_in[5];
    const float* Wqkv  = (const float*)d_in[6];
    const float* bqkv  = (const float*)d_in[7];
    const float* Wo    = (const float*)d_in[8];
    const float* bo    = (const float*)d_in[9];
    const float* ln1g  = (const float*)d_in[10];
    const float* ln1b  = (const float*)d_in[11];
    const float* Wff1  = (const float*)d_in[12];
    const float* bff1  = (const float*)d_in[13];
    const float* Wff2  = (const float*)d_in[14];
    const float* bff2  = (const float*)d_in[15];
    const float* ln2g  = (const float*)d_in[16];
    const float* ln2b  = (const float*)d_in[17];
    const float* Whead = (const float*)d_in[18];
    const float* bhead = (const float*)d_in[19];
    float* out = (float*)d_out;

    // workspace layout (17MB of d_ws):
    //   0- 4MB : h fp32
    //   4- 6MB : hbf bf16
    //   6- 8MB : obf bf16 (attention out)
    //   8- 9MB : transposed bf16 weights (wq 294912B | wo 98304B | w1 196608B | w2 196608B)
    //   9-17MB : shared buf: qkv bf16 (6MB) -> gemm-out fp32 (4MB @9) / ff1-out bf16 (4MB @13)
    char* ws = (char*)d_ws;
    const size_t MB = 1024 * 1024;
    float*          h    = (float*)ws;
    unsigned short* hbf  = (unsigned short*)(ws + 4 * MB);
    unsigned short* obf  = (unsigned short*)(ws + 6 * MB);
    unsigned short* wq   = (unsigned short*)(ws + 8 * MB);
    unsigned short* wo   = (unsigned short*)(ws + 8 * MB + 294912);
    unsigned short* w1   = (unsigned short*)(ws + 8 * MB + 294912 + 98304);
    unsigned short* w2   = (unsigned short*)(ws + 8 * MB + 294912 + 98304 + 196608);
    unsigned short* qkvb = (unsigned short*)(ws + 9 * MB);
    float*          gout = (float*)(ws + 9 * MB);          // reuses qkv region after attn
    unsigned short* fbuf = (unsigned short*)(ws + 13 * MB);

    constexpr int ROWS = 8;
    k_wconv<<<1536, 256, 0, stream>>>(Wqkv, Wo, Wff1, Wff2, wq, wo, w1, w2);
    k_inproj<ROWS><<<NTOK / ROWS, DM, 0, stream>>>(E, rho, W_in1, b_in1, W_in2, b_in2, h, hbf);
    for (int l = 0; l < 3; ++l) {
        k_gemm_mfma<DM, NQKV, false, true><<<dim3(NTOK / 64, NQKV / 64), 256, 0, stream>>>(
            hbf, wq + (size_t)l * NQKV * DM, bqkv + l * NQKV, qkvb);
        k_attn2<<<dim3(TSEQ / QT, 4, NBATCH), 256, 0, stream>>>(qkvb, obf);
        k_gemm_mfma<DM, DM, false, false><<<dim3(NTOK / 64, DM / 64), 256, 0, stream>>>(
            obf, wo + (size_t)l * DM * DM, bo + l * DM, gout);
        k_res_ln<ROWS><<<NTOK / ROWS, DM, 0, stream>>>(gout, ln1g + l * DM, ln1b + l * DM, h, hbf);
        k_gemm_mfma<DM, DFF, true, true><<<dim3(NTOK / 64, DFF / 64), 256, 0, stream>>>(
            hbf, w1 + (size_t)l * DFF * DM, bff1 + l * DFF, fbuf);
        k_gemm_mfma<DFF, DM, false, false><<<dim3(NTOK / 64, DM / 64), 256, 0, stream>>>(
            fbuf, w2 + (size_t)l * DM * DFF, bff2 + l * DM, gout);
        k_res_ln<ROWS><<<NTOK / ROWS, DM, 0, stream>>>(gout, ln2g + l * DM, ln2b + l * DM, h, hbf);
    }
    k_head<<<NTOK / 256, 256, 0, stream>>>(h, Whead, bhead, out);
}

// Round 12
// 295.788 us; speedup vs baseline: 1.9729x; 1.1024x over previous
//
#include <hip/hip_runtime.h>
#include <hip/hip_bf16.h>
#include <math.h>

// Problem constants
#define TSEQ 2048
#define NBATCH 4
#define NTOK (TSEQ * NBATCH)   // 8192
#define DM 128
#define WIN 64
#define DFF 256
#define NQKV 384
#define QT 64                  // query tile for attention

typedef __attribute__((ext_vector_type(8))) short bf16x8;
typedef __attribute__((ext_vector_type(4))) float f32x4;

__device__ __forceinline__ unsigned short f2bf(float f) {
    union { float f; unsigned int u; } v; v.f = f;
    unsigned int r = v.u + 0x7fffu + ((v.u >> 16) & 1u);  // RNE
    return (unsigned short)(r >> 16);
}
__device__ __forceinline__ float bf2f_lo(unsigned int u) {
    union { unsigned int u; float f; } v; v.u = u << 16; return v.f;
}
__device__ __forceinline__ float bf2f_hi(unsigned int u) {
    union { unsigned int u; float f; } v; v.u = u & 0xffff0000u; return v.f;
}

// ---------------- weight convert + transpose to bf16: Wt[l][n][k] = W[l][k][n] ----------------
__global__ void k_wconv(const float* __restrict__ Wqkv, const float* __restrict__ Wo,
                        const float* __restrict__ Wff1, const float* __restrict__ Wff2,
                        unsigned short* __restrict__ wq, unsigned short* __restrict__ wo,
                        unsigned short* __restrict__ w1, unsigned short* __restrict__ w2) {
    int idx = blockIdx.x * 256 + threadIdx.x;
    const int s1 = 3 * 128 * 384, s2 = 3 * 128 * 128, s3 = 3 * 128 * 256, s4 = 3 * 256 * 128;
    if (idx < s1) {                       // K=128, N=384
        int l = idx / (384 * 128), rem = idx % (384 * 128);
        int n = rem / 128, k = rem % 128;
        wq[idx] = f2bf(Wqkv[(size_t)l * 128 * 384 + k * 384 + n]);
    } else if ((idx -= s1) < s2) {        // K=128, N=128
        int l = idx / (128 * 128), rem = idx % (128 * 128);
        int n = rem / 128, k = rem % 128;
        wo[idx] = f2bf(Wo[(size_t)l * 128 * 128 + k * 128 + n]);
    } else if ((idx -= s2) < s3) {        // K=128, N=256
        int l = idx / (256 * 128), rem = idx % (256 * 128);
        int n = rem / 128, k = rem % 128;
        w1[idx] = f2bf(Wff1[(size_t)l * 128 * 256 + k * 256 + n]);
    } else if ((idx -= s3) < s4) {        // K=256, N=128
        int l = idx / (128 * 256), rem = idx % (128 * 256);
        int n = rem / 256, k = rem % 256;
        w2[idx] = f2bf(Wff2[(size_t)l * 256 * 128 + k * 128 + n]);
    }
}

// ---------------- in_proj (Linear->ReLU->Linear) + sinusoidal PE ----------------
template<int ROWS>
__global__ void k_inproj(const float* __restrict__ E, const float* __restrict__ rho,
                         const float* __restrict__ W1, const float* __restrict__ b1,
                         const float* __restrict__ W2, const float* __restrict__ b2,
                         float* __restrict__ h, unsigned short* __restrict__ hbf) {
    const int row0 = blockIdx.x * ROWS;
    const int tid = threadIdx.x;  // 0..127
    __shared__ float x[ROWS][16];
    __shared__ float h1[ROWS][DM];

    for (int idx = tid; idx < ROWS * 16; idx += DM) {
        int r = idx >> 4, c = idx & 15;
        int tok = row0 + r;
        x[r][c] = (c < 8) ? E[(size_t)tok * 8 + c] : rho[(size_t)tok * 8 + (c - 8)];
    }
    __syncthreads();

    float acc[ROWS];
#pragma unroll
    for (int r = 0; r < ROWS; ++r) acc[r] = b1[tid];
    for (int k = 0; k < 16; ++k) {
        float w = W1[k * DM + tid];
#pragma unroll
        for (int r = 0; r < ROWS; ++r) acc[r] += x[r][k] * w;
    }
#pragma unroll
    for (int r = 0; r < ROWS; ++r) h1[r][tid] = fmaxf(acc[r], 0.f);
    __syncthreads();

#pragma unroll
    for (int r = 0; r < ROWS; ++r) acc[r] = b2[tid];
    for (int k = 0; k < DM; ++k) {
        float w = W2[k * DM + tid];
#pragma unroll
        for (int r = 0; r < ROWS; ++r) acc[r] += h1[r][k] * w;
    }

    const float c0 = -0.14391156831212787f;  // -ln(10000)/64
    float dv = __expf(c0 * (float)(tid >> 1));
#pragma unroll
    for (int r = 0; r < ROWS; ++r) {
        int tok = row0 + r;
        int t = tok & (TSEQ - 1);
        float ang = (float)t * dv;
        float pe = (tid & 1) ? cosf(ang) : sinf(ang);
        float v = acc[r] + pe;
        h[(size_t)tok * DM + tid] = v;
        hbf[(size_t)tok * DM + tid] = f2bf(v);
    }
}

// ---------------- MFMA GEMM: C[M,N] = act(Abf[M,K] @ Wt[N,K]^T + bias) ----------------
// 64x64 tile, 4 waves; wave w does rows w*16..w*16+15 of the tile, 4 col-subtiles of 16.
template<int K, int N, bool RELU, bool OUTBF16>
__global__ __launch_bounds__(256) void k_gemm_mfma(
        const unsigned short* __restrict__ A,   // M x K bf16 row-major
        const unsigned short* __restrict__ Wt,  // N x K bf16 row-major (transposed weight)
        const float* __restrict__ bias,         // N
        void* __restrict__ Cout) {              // M x N (fp32 or bf16)
    const int bm0 = blockIdx.x * 64;
    const int bn0 = blockIdx.y * 64;
    const int w = threadIdx.x >> 6;
    const int l = threadIdx.x & 63;
    const int lr = l & 15;
    const int lk = l >> 4;
    const int arow = bm0 + w * 16 + lr;

    bf16x8 aF[K / 32];
    const unsigned short* ap = A + (size_t)arow * K + lk * 8;
#pragma unroll
    for (int ks = 0; ks < K / 32; ++ks)
        aF[ks] = *(const bf16x8*)(ap + ks * 32);

    f32x4 acc[4];
#pragma unroll
    for (int nt = 0; nt < 4; ++nt) {
        float b = bias[bn0 + nt * 16 + lr];
        acc[nt][0] = b; acc[nt][1] = b; acc[nt][2] = b; acc[nt][3] = b;
    }

#pragma unroll
    for (int ks = 0; ks < K / 32; ++ks) {
#pragma unroll
        for (int nt = 0; nt < 4; ++nt) {
            const unsigned short* bp = Wt + (size_t)(bn0 + nt * 16 + lr) * K + ks * 32 + lk * 8;
            bf16x8 bF = *(const bf16x8*)bp;
            acc[nt] = __builtin_amdgcn_mfma_f32_16x16x32_bf16(aF[ks], bF, acc[nt], 0, 0, 0);
        }
    }

#pragma unroll
    for (int nt = 0; nt < 4; ++nt) {
        int col = bn0 + nt * 16 + lr;
#pragma unroll
        for (int r = 0; r < 4; ++r) {
            int row = bm0 + w * 16 + lk * 4 + r;
            float v = acc[nt][r];
            if (RELU) v = fmaxf(v, 0.f);
            if (OUTBF16) ((unsigned short*)Cout)[(size_t)row * N + col] = f2bf(v);
            else ((float*)Cout)[(size_t)row * N + col] = v;
        }
    }
}

// ---------------- fused MFMA GEMM (N=128) + residual + LayerNorm ----------------
// h = LN(h + A @ Wt^T + bias)*g + b, in-place on h (fp32) + hbf (bf16).
// Block = 128 threads (2 waves); wave w owns rows bm0+w*16..+15 across ALL 128 cols
// (8 col-subtiles). Row stats via shfl_xor over the 16 lr-lanes (masks 1,2,4,8).
// Thread owns out (row=w*16+lk*4+r, col=nt*16+lr) uniquely -> in-place safe.
template<int K>
__global__ __launch_bounds__(128) void k_gemm_ln(
        const unsigned short* __restrict__ A,   // M x K bf16
        const unsigned short* __restrict__ Wt,  // 128 x K bf16
        const float* __restrict__ bias,         // 128
        const float* __restrict__ g, const float* __restrict__ be,
        float* __restrict__ h, unsigned short* __restrict__ hbf) {
    const int bm0 = blockIdx.x * 32;
    const int w = threadIdx.x >> 6;
    const int l = threadIdx.x & 63;
    const int lr = l & 15;
    const int lk = l >> 4;
    const int arow = bm0 + w * 16 + lr;

    bf16x8 aF[K / 32];
    const unsigned short* ap = A + (size_t)arow * K + lk * 8;
#pragma unroll
    for (int ks = 0; ks < K / 32; ++ks)
        aF[ks] = *(const bf16x8*)(ap + ks * 32);

    f32x4 acc[8];
#pragma unroll
    for (int nt = 0; nt < 8; ++nt) {
        float b = bias[nt * 16 + lr];
        acc[nt][0] = b; acc[nt][1] = b; acc[nt][2] = b; acc[nt][3] = b;
    }

#pragma unroll
    for (int ks = 0; ks < K / 32; ++ks) {
#pragma unroll
        for (int nt = 0; nt < 8; ++nt) {
            const unsigned short* bp = Wt + (size_t)(nt * 16 + lr) * K + ks * 32 + lk * 8;
            bf16x8 bF = *(const bf16x8*)bp;
            acc[nt] = __builtin_amdgcn_mfma_f32_16x16x32_bf16(aF[ks], bF, acc[nt], 0, 0, 0);
        }
    }

    // residual add (each thread owns its (row,col) elements)
#pragma unroll
    for (int nt = 0; nt < 8; ++nt) {
        int col = nt * 16 + lr;
#pragma unroll
        for (int r = 0; r < 4; ++r) {
            int row = bm0 + w * 16 + lk * 4 + r;
            acc[nt][r] += h[(size_t)row * DM + col];
        }
    }

    // row stats: partial over this lane's 8 cols, reduce across 16 lr-lanes
    float s[4], s2[4];
#pragma unroll
    for (int r = 0; r < 4; ++r) {
        float a0 = 0.f, a1 = 0.f;
#pragma unroll
        for (int nt = 0; nt < 8; ++nt) { a0 += acc[nt][r]; a1 += acc[nt][r] * acc[nt][r]; }
        s[r] = a0; s2[r] = a1;
    }
#pragma unroll
    for (int off = 8; off; off >>= 1) {
#pragma unroll
        for (int r = 0; r < 4; ++r) {
            s[r]  += __shfl_xor(s[r],  off);
            s2[r] += __shfl_xor(s2[r], off);
        }
    }
    float mean[4], rstd[4];
#pragma unroll
    for (int r = 0; r < 4; ++r) {
        mean[r] = s[r] * (1.f / DM);
        float var = s2[r] * (1.f / DM) - mean[r] * mean[r];
        rstd[r] = rsqrtf(var + 1e-5f);
    }

#pragma unroll
    for (int nt = 0; nt < 8; ++nt) {
        int col = nt * 16 + lr;
        float gg = g[col], bb = be[col];
#pragma unroll
        for (int r = 0; r < 4; ++r) {
            int row = bm0 + w * 16 + lk * 4 + r;
            float v = (acc[nt][r] - mean[r]) * rstd[r] * gg + bb;
            h[(size_t)row * DM + col] = v;
            hbf[(size_t)row * DM + col] = f2bf(v);
        }
    }
}

// ---------------- tiled banded attention (bf16 qkv in, bf16 o out) ----------------
__global__ void k_attn2(const unsigned short* __restrict__ qkv, unsigned short* __restrict__ o) {
    const int t0   = blockIdx.x * QT;
    const int head = blockIdx.y;
    const int b    = blockIdx.z;
    const int tid  = threadIdx.x;
    const int q    = tid >> 2;
    const int s    = tid & 3;

    __shared__ float kbuf[127][36];
    __shared__ float vbuf[127][36];

    // stage K/V (tokens j = t0-63 .. t0+63) as fp32 in LDS; zero-fill j<0
    for (int idx = tid; idx < 127 * 4; idx += 256) {
        int kb = idx >> 2, c = idx & 3;  // c: 8-dim group
        int j = t0 - 63 + kb;
        uint4 kv = make_uint4(0, 0, 0, 0), vv = make_uint4(0, 0, 0, 0);
        if (j >= 0) {
            const unsigned short* base = qkv + ((size_t)(b * TSEQ + j)) * NQKV + head * 32 + c * 8;
            kv = *(const uint4*)(base + 128);
            vv = *(const uint4*)(base + 256);
        }
        float* kd = &kbuf[kb][c * 8];
        float* vd = &vbuf[kb][c * 8];
        kd[0] = bf2f_lo(kv.x); kd[1] = bf2f_hi(kv.x); kd[2] = bf2f_lo(kv.y); kd[3] = bf2f_hi(kv.y);
        kd[4] = bf2f_lo(kv.z); kd[5] = bf2f_hi(kv.z); kd[6] = bf2f_lo(kv.w); kd[7] = bf2f_hi(kv.w);
        vd[0] = bf2f_lo(vv.x); vd[1] = bf2f_hi(vv.x); vd[2] = bf2f_lo(vv.y); vd[3] = bf2f_hi(vv.y);
        vd[4] = bf2f_lo(vv.z); vd[5] = bf2f_hi(vv.z); vd[6] = bf2f_lo(vv.w); vd[7] = bf2f_hi(vv.w);
    }

    // Q row into registers
    float qreg[32];
    {
        const unsigned short* qp = qkv + ((size_t)(b * TSEQ + t0 + q)) * NQKV + head * 32;
#pragma unroll
        for (int c = 0; c < 4; ++c) {
            uint4 u = *(const uint4*)(qp + c * 8);
            float* qd = &qreg[c * 8];
            qd[0] = bf2f_lo(u.x); qd[1] = bf2f_hi(u.x); qd[2] = bf2f_lo(u.y); qd[3] = bf2f_hi(u.y);
            qd[4] = bf2f_lo(u.z); qd[5] = bf2f_hi(u.z); qd[6] = bf2f_lo(u.w); qd[7] = bf2f_hi(u.w);
        }
    }
    __syncthreads();

    const float scale = 0.17677669529663687f;  // 1/sqrt(32)
    float sc[16];
#pragma unroll
    for (int kk = 0; kk < 16; ++kk) {
        int w = s + 4 * kk;
        int kb = q + w;
        float acc = 0.f;
#pragma unroll
        for (int d = 0; d < 32; ++d) acc += qreg[d] * kbuf[kb][d];
        int j = t0 + q - 63 + w;
        sc[kk] = (j >= 0) ? acc * scale : -1e30f;
    }

    float m = sc[0];
#pragma unroll
    for (int kk = 1; kk < 16; ++kk) m = fmaxf(m, sc[kk]);
    m = fmaxf(m, __shfl_xor(m, 1));
    m = fmaxf(m, __shfl_xor(m, 2));
    float sum = 0.f;
#pragma unroll
    for (int kk = 0; kk < 16; ++kk) { sc[kk] = __expf(sc[kk] - m); sum += sc[kk]; }
    sum += __shfl_xor(sum, 1);
    sum += __shfl_xor(sum, 2);
    const float inv = 1.f / sum;

    float acc[32];
#pragma unroll
    for (int d = 0; d < 32; ++d) acc[d] = 0.f;
#pragma unroll
    for (int kk = 0; kk < 16; ++kk) {
        float p = sc[kk] * inv;
        int kb = q + s + 4 * kk;
#pragma unroll
        for (int d = 0; d < 32; ++d) acc[d] += p * vbuf[kb][d];
    }
#pragma unroll
    for (int d = 0; d < 32; ++d) {
        acc[d] += __shfl_xor(acc[d], 1);
        acc[d] += __shfl_xor(acc[d], 2);
    }
    if (s == 0) {
        unsigned short* op = o + ((size_t)(b * TSEQ + t0 + q)) * DM + head * 32;
#pragma unroll
        for (int d = 0; d < 32; d += 2) {
            unsigned int u = ((unsigned int)f2bf(acc[d + 1]) << 16) | f2bf(acc[d]);
            *(unsigned int*)(op + d) = u;
        }
    }
}

// ---------------- output head: (NTOK,128) @ (128,8) + b ----------------
__global__ void k_head(const float* __restrict__ h, const float* __restrict__ W,
                       const float* __restrict__ bias, float* __restrict__ out) {
    const int tok = blockIdx.x * blockDim.x + threadIdx.x;
    if (tok >= NTOK) return;
    float acc[8];
#pragma unroll
    for (int r = 0; r < 8; ++r) acc[r] = bias[r];
    for (int k = 0; k < DM; ++k) {
        float hv = h[(size_t)tok * DM + k];
#pragma unroll
        for (int r = 0; r < 8; ++r) acc[r] += hv * W[k * 8 + r];
    }
#pragma unroll
    for (int r = 0; r < 8; ++r) out[(size_t)tok * 8 + r] = acc[r];
}

extern "C" void kernel_launch(void* const* d_in, const int* in_sizes, int n_in,
                              void* d_out, int out_size, void* d_ws, size_t ws_size,
                              hipStream_t stream) {
    const float* E     = (const float*)d_in[0];
    const float* rho   = (const float*)d_in[1];
    const float* W_in1 = (const float*)d_in[2];
    const float* b_in1 = (const float*)d_in[3];
    const float* W_in2 = (const float*)d_in[4];
    const float* b_in2 = (const float*)d_in[5];
    const float* Wqkv  = (const float*)d_in[6];
    const float* bqkv  = (const float*)d_in[7];
    const float* Wo    = (const float*)d_in[8];
    const float* bo    = (const float*)d_in[9];
    const float* ln1g  = (const float*)d_in[10];
    const float* ln1b  = (const float*)d_in[11];
    const float* Wff1  = (const float*)d_in[12];
    const float* bff1  = (const float*)d_in[13];
    const float* Wff2  = (const float*)d_in[14];
    const float* bff2  = (const float*)d_in[15];
    const float* ln2g  = (const float*)d_in[16];
    const float* ln2b  = (const float*)d_in[17];
    const float* Whead = (const float*)d_in[18];
    const float* bhead = (const float*)d_in[19];
    float* out = (float*)d_out;

    // workspace layout (17MB of d_ws):
    //   0- 4MB : h fp32
    //   4- 6MB : hbf bf16
    //   6- 8MB : obf bf16 (attention out)
    //   8- 9MB : transposed bf16 weights (wq | wo | w1 | w2)
    //   9-15MB : qkv bf16 (live: qkv gemm -> attn)
    //  13-17MB : fbuf bf16 (live: ff1 -> ff2; disjoint in time from qkvb)
    char* ws = (char*)d_ws;
    const size_t MB = 1024 * 1024;
    float*          h    = (float*)ws;
    unsigned short* hbf  = (unsigned short*)(ws + 4 * MB);
    unsigned short* obf  = (unsigned short*)(ws + 6 * MB);
    unsigned short* wq   = (unsigned short*)(ws + 8 * MB);
    unsigned short* wo   = (unsigned short*)(ws + 8 * MB + 294912);
    unsigned short* w1   = (unsigned short*)(ws + 8 * MB + 294912 + 98304);
    unsigned short* w2   = (unsigned short*)(ws + 8 * MB + 294912 + 98304 + 196608);
    unsigned short* qkvb = (unsigned short*)(ws + 9 * MB);
    unsigned short* fbuf = (unsigned short*)(ws + 13 * MB);

    constexpr int ROWS = 8;
    k_wconv<<<1536, 256, 0, stream>>>(Wqkv, Wo, Wff1, Wff2, wq, wo, w1, w2);
    k_inproj<ROWS><<<NTOK / ROWS, DM, 0, stream>>>(E, rho, W_in1, b_in1, W_in2, b_in2, h, hbf);
    for (int l = 0; l < 3; ++l) {
        k_gemm_mfma<DM, NQKV, false, true><<<dim3(NTOK / 64, NQKV / 64), 256, 0, stream>>>(
            hbf, wq + (size_t)l * NQKV * DM, bqkv + l * NQKV, qkvb);
        k_attn2<<<dim3(TSEQ / QT, 4, NBATCH), 256, 0, stream>>>(qkvb, obf);
        k_gemm_ln<DM><<<NTOK / 32, 128, 0, stream>>>(
            obf, wo + (size_t)l * DM * DM, bo + l * DM, ln1g + l * DM, ln1b + l * DM, h, hbf);
        k_gemm_mfma<DM, DFF, true, true><<<dim3(NTOK / 64, DFF / 64), 256, 0, stream>>>(
            hbf, w1 + (size_t)l * DFF * DM, bff1 + l * DFF, fbuf);
        k_gemm_ln<DFF><<<NTOK / 32, 128, 0, stream>>>(
            fbuf, w2 + (size_t)l * DM * DFF, bff2 + l * DM, ln2g + l * DM, ln2b + l * DM, h, hbf);
    }
    k_head<<<NTOK / 256, 256, 0, stream>>>(h, Whead, bhead, out);
}

// Round 16
// 288.741 us; speedup vs baseline: 2.0210x; 1.0244x over previous
//
#include <hip/hip_runtime.h>
#include <hip/hip_bf16.h>
#include <math.h>

// Problem constants
#define TSEQ 2048
#define NBATCH 4
#define NTOK (TSEQ * NBATCH)   // 8192
#define DM 128
#define WIN 64
#define DFF 256
#define NQKV 384
#define QT 64                  // query tile for attention

typedef __attribute__((ext_vector_type(8))) short bf16x8;
typedef __attribute__((ext_vector_type(4))) float f32x4;

__device__ __forceinline__ unsigned short f2bf(float f) {
    union { float f; unsigned int u; } v; v.f = f;
    unsigned int r = v.u + 0x7fffu + ((v.u >> 16) & 1u);  // RNE
    return (unsigned short)(r >> 16);
}
__device__ __forceinline__ float bf2f_lo(unsigned int u) {
    union { unsigned int u; float f; } v; v.u = u << 16; return v.f;
}
__device__ __forceinline__ float bf2f_hi(unsigned int u) {
    union { unsigned int u; float f; } v; v.u = u & 0xffff0000u; return v.f;
}

// ---------------- weight convert + transpose to bf16: Wt[l][n][k] = W[l][k][n] ----------------
__global__ void k_wconv(const float* __restrict__ Wqkv, const float* __restrict__ Wo,
                        const float* __restrict__ Wff1, const float* __restrict__ Wff2,
                        unsigned short* __restrict__ wq, unsigned short* __restrict__ wo,
                        unsigned short* __restrict__ w1, unsigned short* __restrict__ w2) {
    int idx = blockIdx.x * 256 + threadIdx.x;
    const int s1 = 3 * 128 * 384, s2 = 3 * 128 * 128, s3 = 3 * 128 * 256, s4 = 3 * 256 * 128;
    if (idx < s1) {                       // K=128, N=384
        int l = idx / (384 * 128), rem = idx % (384 * 128);
        int n = rem / 128, k = rem % 128;
        wq[idx] = f2bf(Wqkv[(size_t)l * 128 * 384 + k * 384 + n]);
    } else if ((idx -= s1) < s2) {        // K=128, N=128
        int l = idx / (128 * 128), rem = idx % (128 * 128);
        int n = rem / 128, k = rem % 128;
        wo[idx] = f2bf(Wo[(size_t)l * 128 * 128 + k * 128 + n]);
    } else if ((idx -= s2) < s3) {        // K=128, N=256
        int l = idx / (256 * 128), rem = idx % (256 * 128);
        int n = rem / 128, k = rem % 128;
        w1[idx] = f2bf(Wff1[(size_t)l * 128 * 256 + k * 256 + n]);
    } else if ((idx -= s3) < s4) {        // K=256, N=128
        int l = idx / (128 * 256), rem = idx % (128 * 256);
        int n = rem / 256, k = rem % 256;
        w2[idx] = f2bf(Wff2[(size_t)l * 256 * 128 + k * 128 + n]);
    }
}

// ---------------- in_proj (Linear->ReLU->Linear) + sinusoidal PE ----------------
template<int ROWS>
__global__ void k_inproj(const float* __restrict__ E, const float* __restrict__ rho,
                         const float* __restrict__ W1, const float* __restrict__ b1,
                         const float* __restrict__ W2, const float* __restrict__ b2,
                         float* __restrict__ h, unsigned short* __restrict__ hbf) {
    const int row0 = blockIdx.x * ROWS;
    const int tid = threadIdx.x;  // 0..127
    __shared__ float x[ROWS][16];
    __shared__ float h1[ROWS][DM];

    for (int idx = tid; idx < ROWS * 16; idx += DM) {
        int r = idx >> 4, c = idx & 15;
        int tok = row0 + r;
        x[r][c] = (c < 8) ? E[(size_t)tok * 8 + c] : rho[(size_t)tok * 8 + (c - 8)];
    }
    __syncthreads();

    float acc[ROWS];
#pragma unroll
    for (int r = 0; r < ROWS; ++r) acc[r] = b1[tid];
    for (int k = 0; k < 16; ++k) {
        float w = W1[k * DM + tid];
#pragma unroll
        for (int r = 0; r < ROWS; ++r) acc[r] += x[r][k] * w;
    }
#pragma unroll
    for (int r = 0; r < ROWS; ++r) h1[r][tid] = fmaxf(acc[r], 0.f);
    __syncthreads();

#pragma unroll
    for (int r = 0; r < ROWS; ++r) acc[r] = b2[tid];
    for (int k = 0; k < DM; ++k) {
        float w = W2[k * DM + tid];
#pragma unroll
        for (int r = 0; r < ROWS; ++r) acc[r] += h1[r][k] * w;
    }

    const float c0 = -0.14391156831212787f;  // -ln(10000)/64
    float dv = __expf(c0 * (float)(tid >> 1));
#pragma unroll
    for (int r = 0; r < ROWS; ++r) {
        int tok = row0 + r;
        int t = tok & (TSEQ - 1);
        float ang = (float)t * dv;
        float pe = (tid & 1) ? cosf(ang) : sinf(ang);
        float v = acc[r] + pe;
        h[(size_t)tok * DM + tid] = v;
        hbf[(size_t)tok * DM + tid] = f2bf(v);
    }
}

// ---------------- MFMA GEMM: C[M,N] = act(Abf[M,K] @ Wt[N,K]^T + bias) ----------------
// 64x64 tile, 4 waves; wave w does rows w*16..w*16+15 of the tile, 4 col-subtiles of 16.
template<int K, int N, bool RELU, bool OUTBF16>
__global__ __launch_bounds__(256) void k_gemm_mfma(
        const unsigned short* __restrict__ A,   // M x K bf16 row-major
        const unsigned short* __restrict__ Wt,  // N x K bf16 row-major (transposed weight)
        const float* __restrict__ bias,         // N
        void* __restrict__ Cout) {              // M x N (fp32 or bf16)
    const int bm0 = blockIdx.x * 64;
    const int bn0 = blockIdx.y * 64;
    const int w = threadIdx.x >> 6;
    const int l = threadIdx.x & 63;
    const int lr = l & 15;
    const int lk = l >> 4;
    const int arow = bm0 + w * 16 + lr;

    bf16x8 aF[K / 32];
    const unsigned short* ap = A + (size_t)arow * K + lk * 8;
#pragma unroll
    for (int ks = 0; ks < K / 32; ++ks)
        aF[ks] = *(const bf16x8*)(ap + ks * 32);

    f32x4 acc[4];
#pragma unroll
    for (int nt = 0; nt < 4; ++nt) {
        float b = bias[bn0 + nt * 16 + lr];
        acc[nt][0] = b; acc[nt][1] = b; acc[nt][2] = b; acc[nt][3] = b;
    }

#pragma unroll
    for (int ks = 0; ks < K / 32; ++ks) {
#pragma unroll
        for (int nt = 0; nt < 4; ++nt) {
            const unsigned short* bp = Wt + (size_t)(bn0 + nt * 16 + lr) * K + ks * 32 + lk * 8;
            bf16x8 bF = *(const bf16x8*)bp;
            acc[nt] = __builtin_amdgcn_mfma_f32_16x16x32_bf16(aF[ks], bF, acc[nt], 0, 0, 0);
        }
    }

#pragma unroll
    for (int nt = 0; nt < 4; ++nt) {
        int col = bn0 + nt * 16 + lr;
#pragma unroll
        for (int r = 0; r < 4; ++r) {
            int row = bm0 + w * 16 + lk * 4 + r;
            float v = acc[nt][r];
            if (RELU) v = fmaxf(v, 0.f);
            if (OUTBF16) ((unsigned short*)Cout)[(size_t)row * N + col] = f2bf(v);
            else ((float*)Cout)[(size_t)row * N + col] = v;
        }
    }
}

// ---------------- fused MFMA GEMM (N=128) + residual + LayerNorm ----------------
// h = LN(h + A @ Wt^T + bias)*g + b, in-place on h (fp32) + hbf (bf16).
template<int K>
__global__ __launch_bounds__(128) void k_gemm_ln(
        const unsigned short* __restrict__ A,   // M x K bf16
        const unsigned short* __restrict__ Wt,  // 128 x K bf16
        const float* __restrict__ bias,         // 128
        const float* __restrict__ g, const float* __restrict__ be,
        float* __restrict__ h, unsigned short* __restrict__ hbf) {
    const int bm0 = blockIdx.x * 32;
    const int w = threadIdx.x >> 6;
    const int l = threadIdx.x & 63;
    const int lr = l & 15;
    const int lk = l >> 4;
    const int arow = bm0 + w * 16 + lr;

    bf16x8 aF[K / 32];
    const unsigned short* ap = A + (size_t)arow * K + lk * 8;
#pragma unroll
    for (int ks = 0; ks < K / 32; ++ks)
        aF[ks] = *(const bf16x8*)(ap + ks * 32);

    f32x4 acc[8];
#pragma unroll
    for (int nt = 0; nt < 8; ++nt) {
        float b = bias[nt * 16 + lr];
        acc[nt][0] = b; acc[nt][1] = b; acc[nt][2] = b; acc[nt][3] = b;
    }

#pragma unroll
    for (int ks = 0; ks < K / 32; ++ks) {
#pragma unroll
        for (int nt = 0; nt < 8; ++nt) {
            const unsigned short* bp = Wt + (size_t)(nt * 16 + lr) * K + ks * 32 + lk * 8;
            bf16x8 bF = *(const bf16x8*)bp;
            acc[nt] = __builtin_amdgcn_mfma_f32_16x16x32_bf16(aF[ks], bF, acc[nt], 0, 0, 0);
        }
    }

#pragma unroll
    for (int nt = 0; nt < 8; ++nt) {
        int col = nt * 16 + lr;
#pragma unroll
        for (int r = 0; r < 4; ++r) {
            int row = bm0 + w * 16 + lk * 4 + r;
            acc[nt][r] += h[(size_t)row * DM + col];
        }
    }

    float s[4], s2[4];
#pragma unroll
    for (int r = 0; r < 4; ++r) {
        float a0 = 0.f, a1 = 0.f;
#pragma unroll
        for (int nt = 0; nt < 8; ++nt) { a0 += acc[nt][r]; a1 += acc[nt][r] * acc[nt][r]; }
        s[r] = a0; s2[r] = a1;
    }
#pragma unroll
    for (int off = 8; off; off >>= 1) {
#pragma unroll
        for (int r = 0; r < 4; ++r) {
            s[r]  += __shfl_xor(s[r],  off);
            s2[r] += __shfl_xor(s2[r], off);
        }
    }
    float mean[4], rstd[4];
#pragma unroll
    for (int r = 0; r < 4; ++r) {
        mean[r] = s[r] * (1.f / DM);
        float var = s2[r] * (1.f / DM) - mean[r] * mean[r];
        rstd[r] = rsqrtf(var + 1e-5f);
    }

#pragma unroll
    for (int nt = 0; nt < 8; ++nt) {
        int col = nt * 16 + lr;
        float gg = g[col], bb = be[col];
#pragma unroll
        for (int r = 0; r < 4; ++r) {
            int row = bm0 + w * 16 + lk * 4 + r;
            float v = (acc[nt][r] - mean[r]) * rstd[r] * gg + bb;
            h[(size_t)row * DM + col] = v;
            hbf[(size_t)row * DM + col] = f2bf(v);
        }
    }
}

// ---------------- fused FF block: h = LN(h + relu(hbf@W1^T+b1)@W2^T+b2) ----------------
// Phase 1 uses SWAPPED mfma operands (W as A-op, activation as B-op) so D = ff1^T in
// registers: thread owns (n = nt*16+lk*4+r  [4 consecutive], m = w*16+lr) -> one 8B
// LDS write per nt. LDS a2[32][264] (+8 bf16 pad: row stride 132 words ≡ 4 mod 32 ->
// 2-way bank aliasing, free). Phase 2 = standard K=256 GEMM from LDS + residual + LN.
__global__ __launch_bounds__(128) void k_ff_fused(
        const unsigned short* __restrict__ A,    // M x 128 bf16 (hbf)
        const unsigned short* __restrict__ W1t,  // 256 x 128 bf16
        const float* __restrict__ b1,            // 256
        const unsigned short* __restrict__ W2t,  // 128 x 256 bf16
        const float* __restrict__ b2,            // 128
        const float* __restrict__ g, const float* __restrict__ be,
        float* __restrict__ h, unsigned short* __restrict__ hbf) {
    const int bm0 = blockIdx.x * 32;
    const int w = threadIdx.x >> 6;
    const int l = threadIdx.x & 63;
    const int lr = l & 15;
    const int lk = l >> 4;

    __shared__ unsigned short a2[32][264];

    // ---- phase 1: ff1^T into LDS ----
    const int arow = bm0 + w * 16 + lr;
    bf16x8 aF[4];
    const unsigned short* ap = A + (size_t)arow * DM + lk * 8;
#pragma unroll
    for (int ks = 0; ks < 4; ++ks)
        aF[ks] = *(const bf16x8*)(ap + ks * 32);

    f32x4 acc[16];
#pragma unroll
    for (int nt = 0; nt < 16; ++nt) { acc[nt][0] = 0.f; acc[nt][1] = 0.f; acc[nt][2] = 0.f; acc[nt][3] = 0.f; }

#pragma unroll
    for (int ks = 0; ks < 4; ++ks) {
#pragma unroll
        for (int nt = 0; nt < 16; ++nt) {
            const unsigned short* wp = W1t + (size_t)(nt * 16 + lr) * DM + ks * 32 + lk * 8;
            bf16x8 wF = *(const bf16x8*)wp;
            // swapped operands: D[n][m], n = A-op row (W1t row), m = B-op col (act row)
            acc[nt] = __builtin_amdgcn_mfma_f32_16x16x32_bf16(wF, aF[ks], acc[nt], 0, 0, 0);
        }
    }

    const int mloc = w * 16 + lr;
#pragma unroll
    for (int nt = 0; nt < 16; ++nt) {
        int n0 = nt * 16 + lk * 4;
        uint2 pk;
        float v0 = fmaxf(acc[nt][0] + b1[n0 + 0], 0.f);
        float v1 = fmaxf(acc[nt][1] + b1[n0 + 1], 0.f);
        float v2 = fmaxf(acc[nt][2] + b1[n0 + 2], 0.f);
        float v3 = fmaxf(acc[nt][3] + b1[n0 + 3], 0.f);
        pk.x = (unsigned int)f2bf(v0) | ((unsigned int)f2bf(v1) << 16);
        pk.y = (unsigned int)f2bf(v2) | ((unsigned int)f2bf(v3) << 16);
        *(uint2*)&a2[mloc][n0] = pk;
    }
    __syncthreads();

    // ---- phase 2: K=256 GEMM from LDS + residual + LN ----
    bf16x8 aF2[8];
#pragma unroll
    for (int ks = 0; ks < 8; ++ks)
        aF2[ks] = *(const bf16x8*)&a2[w * 16 + lr][ks * 32 + lk * 8];

    f32x4 acc2[8];
#pragma unroll
    for (int nt = 0; nt < 8; ++nt) {
        float b = b2[nt * 16 + lr];
        acc2[nt][0] = b; acc2[nt][1] = b; acc2[nt][2] = b; acc2[nt][3] = b;
    }

#pragma unroll
    for (int ks = 0; ks < 8; ++ks) {
#pragma unroll
        for (int nt = 0; nt < 8; ++nt) {
            const unsigned short* bp = W2t + (size_t)(nt * 16 + lr) * DFF + ks * 32 + lk * 8;
            bf16x8 bF = *(const bf16x8*)bp;
            acc2[nt] = __builtin_amdgcn_mfma_f32_16x16x32_bf16(aF2[ks], bF, acc2[nt], 0, 0, 0);
        }
    }

#pragma unroll
    for (int nt = 0; nt < 8; ++nt) {
        int col = nt * 16 + lr;
#pragma unroll
        for (int r = 0; r < 4; ++r) {
            int row = bm0 + w * 16 + lk * 4 + r;
            acc2[nt][r] += h[(size_t)row * DM + col];
        }
    }

    float s[4], s2[4];
#pragma unroll
    for (int r = 0; r < 4; ++r) {
        float a0 = 0.f, a1 = 0.f;
#pragma unroll
        for (int nt = 0; nt < 8; ++nt) { a0 += acc2[nt][r]; a1 += acc2[nt][r] * acc2[nt][r]; }
        s[r] = a0; s2[r] = a1;
    }
#pragma unroll
    for (int off = 8; off; off >>= 1) {
#pragma unroll
        for (int r = 0; r < 4; ++r) {
            s[r]  += __shfl_xor(s[r],  off);
            s2[r] += __shfl_xor(s2[r], off);
        }
    }
    float mean[4], rstd[4];
#pragma unroll
    for (int r = 0; r < 4; ++r) {
        mean[r] = s[r] * (1.f / DM);
        float var = s2[r] * (1.f / DM) - mean[r] * mean[r];
        rstd[r] = rsqrtf(var + 1e-5f);
    }

#pragma unroll
    for (int nt = 0; nt < 8; ++nt) {
        int col = nt * 16 + lr;
        float gg = g[col], bb = be[col];
#pragma unroll
        for (int r = 0; r < 4; ++r) {
            int row = bm0 + w * 16 + lk * 4 + r;
            float v = (acc2[nt][r] - mean[r]) * rstd[r] * gg + bb;
            h[(size_t)row * DM + col] = v;
            hbf[(size_t)row * DM + col] = f2bf(v);
        }
    }
}

// ---------------- tiled banded attention (bf16 qkv in, bf16 o out) ----------------
__global__ void k_attn2(const unsigned short* __restrict__ qkv, unsigned short* __restrict__ o) {
    const int t0   = blockIdx.x * QT;
    const int head = blockIdx.y;
    const int b    = blockIdx.z;
    const int tid  = threadIdx.x;
    const int q    = tid >> 2;
    const int s    = tid & 3;

    __shared__ float kbuf[127][36];
    __shared__ float vbuf[127][36];

    // stage K/V (tokens j = t0-63 .. t0+63) as fp32 in LDS; zero-fill j<0
    for (int idx = tid; idx < 127 * 4; idx += 256) {
        int kb = idx >> 2, c = idx & 3;  // c: 8-dim group
        int j = t0 - 63 + kb;
        uint4 kv = make_uint4(0, 0, 0, 0), vv = make_uint4(0, 0, 0, 0);
        if (j >= 0) {
            const unsigned short* base = qkv + ((size_t)(b * TSEQ + j)) * NQKV + head * 32 + c * 8;
            kv = *(const uint4*)(base + 128);
            vv = *(const uint4*)(base + 256);
        }
        float* kd = &kbuf[kb][c * 8];
        float* vd = &vbuf[kb][c * 8];
        kd[0] = bf2f_lo(kv.x); kd[1] = bf2f_hi(kv.x); kd[2] = bf2f_lo(kv.y); kd[3] = bf2f_hi(kv.y);
        kd[4] = bf2f_lo(kv.z); kd[5] = bf2f_hi(kv.z); kd[6] = bf2f_lo(kv.w); kd[7] = bf2f_hi(kv.w);
        vd[0] = bf2f_lo(vv.x); vd[1] = bf2f_hi(vv.x); vd[2] = bf2f_lo(vv.y); vd[3] = bf2f_hi(vv.y);
        vd[4] = bf2f_lo(vv.z); vd[5] = bf2f_hi(vv.z); vd[6] = bf2f_lo(vv.w); vd[7] = bf2f_hi(vv.w);
    }

    // Q row into registers
    float qreg[32];
    {
        const unsigned short* qp = qkv + ((size_t)(b * TSEQ + t0 + q)) * NQKV + head * 32;
#pragma unroll
        for (int c = 0; c < 4; ++c) {
            uint4 u = *(const uint4*)(qp + c * 8);
            float* qd = &qreg[c * 8];
            qd[0] = bf2f_lo(u.x); qd[1] = bf2f_hi(u.x); qd[2] = bf2f_lo(u.y); qd[3] = bf2f_hi(u.y);
            qd[4] = bf2f_lo(u.z); qd[5] = bf2f_hi(u.z); qd[6] = bf2f_lo(u.w); qd[7] = bf2f_hi(u.w);
        }
    }
    __syncthreads();

    const float scale = 0.17677669529663687f;  // 1/sqrt(32)
    float sc[16];
#pragma unroll
    for (int kk = 0; kk < 16; ++kk) {
        int w = s + 4 * kk;
        int kb = q + w;
        float acc = 0.f;
#pragma unroll
        for (int d = 0; d < 32; ++d) acc += qreg[d] * kbuf[kb][d];
        int j = t0 + q - 63 + w;
        sc[kk] = (j >= 0) ? acc * scale : -1e30f;
    }

    float m = sc[0];
#pragma unroll
    for (int kk = 1; kk < 16; ++kk) m = fmaxf(m, sc[kk]);
    m = fmaxf(m, __shfl_xor(m, 1));
    m = fmaxf(m, __shfl_xor(m, 2));
    float sum = 0.f;
#pragma unroll
    for (int kk = 0; kk < 16; ++kk) { sc[kk] = __expf(sc[kk] - m); sum += sc[kk]; }
    sum += __shfl_xor(sum, 1);
    sum += __shfl_xor(sum, 2);
    const float inv = 1.f / sum;

    float acc[32];
#pragma unroll
    for (int d = 0; d < 32; ++d) acc[d] = 0.f;
#pragma unroll
    for (int kk = 0; kk < 16; ++kk) {
        float p = sc[kk] * inv;
        int kb = q + s + 4 * kk;
#pragma unroll
        for (int d = 0; d < 32; ++d) acc[d] += p * vbuf[kb][d];
    }
#pragma unroll
    for (int d = 0; d < 32; ++d) {
        acc[d] += __shfl_xor(acc[d], 1);
        acc[d] += __shfl_xor(acc[d], 2);
    }
    if (s == 0) {
        unsigned short* op = o + ((size_t)(b * TSEQ + t0 + q)) * DM + head * 32;
#pragma unroll
        for (int d = 0; d < 32; d += 2) {
            unsigned int u = ((unsigned int)f2bf(acc[d + 1]) << 16) | f2bf(acc[d]);
            *(unsigned int*)(op + d) = u;
        }
    }
}

// ---------------- output head: (NTOK,128) @ (128,8) + b ----------------
__global__ void k_head(const float* __restrict__ h, const float* __restrict__ W,
                       const float* __restrict__ bias, float* __restrict__ out) {
    const int tok = blockIdx.x * blockDim.x + threadIdx.x;
    if (tok >= NTOK) return;
    float acc[8];
#pragma unroll
    for (int r = 0; r < 8; ++r) acc[r] = bias[r];
    for (int k = 0; k < DM; ++k) {
        float hv = h[(size_t)tok * DM + k];
#pragma unroll
        for (int r = 0; r < 8; ++r) acc[r] += hv * W[k * 8 + r];
    }
#pragma unroll
    for (int r = 0; r < 8; ++r) out[(size_t)tok * 8 + r] = acc[r];
}

extern "C" void kernel_launch(void* const* d_in, const int* in_sizes, int n_in,
                              void* d_out, int out_size, void* d_ws, size_t ws_size,
                              hipStream_t stream) {
    const float* E     = (const float*)d_in[0];
    const float* rho   = (const float*)d_in[1];
    const float* W_in1 = (const float*)d_in[2];
    const float* b_in1 = (const float*)d_in[3];
    const float* W_in2 = (const float*)d_in[4];
    const float* b_in2 = (const float*)d_in[5];
    const float* Wqkv  = (const float*)d_in[6];
    const float* bqkv  = (const float*)d_in[7];
    const float* Wo    = (const float*)d_in[8];
    const float* bo    = (const float*)d_in[9];
    const float* ln1g  = (const float*)d_in[10];
    const float* ln1b  = (const float*)d_in[11];
    const float* Wff1  = (const float*)d_in[12];
    const float* bff1  = (const float*)d_in[13];
    const float* Wff2  = (const float*)d_in[14];
    const float* bff2  = (const float*)d_in[15];
    const float* ln2g  = (const float*)d_in[16];
    const float* ln2b  = (const float*)d_in[17];
    const float* Whead = (const float*)d_in[18];
    const float* bhead = (const float*)d_in[19];
    float* out = (float*)d_out;

    // workspace layout (15MB of d_ws):
    //   0- 4MB : h fp32
    //   4- 6MB : hbf bf16
    //   6- 8MB : obf bf16 (attention out)
    //   8- 9MB : transposed bf16 weights (wq | wo | w1 | w2)
    //   9-15MB : qkvb bf16 (live: qkv gemm -> attn)
    char* ws = (char*)d_ws;
    const size_t MB = 1024 * 1024;
    float*          h    = (float*)ws;
    unsigned short* hbf  = (unsigned short*)(ws + 4 * MB);
    unsigned short* obf  = (unsigned short*)(ws + 6 * MB);
    unsigned short* wq   = (unsigned short*)(ws + 8 * MB);
    unsigned short* wo   = (unsigned short*)(ws + 8 * MB + 294912);
    unsigned short* w1   = (unsigned short*)(ws + 8 * MB + 294912 + 98304);
    unsigned short* w2   = (unsigned short*)(ws + 8 * MB + 294912 + 98304 + 196608);
    unsigned short* qkvb = (unsigned short*)(ws + 9 * MB);

    constexpr int ROWS = 8;
    k_wconv<<<1536, 256, 0, stream>>>(Wqkv, Wo, Wff1, Wff2, wq, wo, w1, w2);
    k_inproj<ROWS><<<NTOK / ROWS, DM, 0, stream>>>(E, rho, W_in1, b_in1, W_in2, b_in2, h, hbf);
    for (int l = 0; l < 3; ++l) {
        k_gemm_mfma<DM, NQKV, false, true><<<dim3(NTOK / 64, NQKV / 64), 256, 0, stream>>>(
            hbf, wq + (size_t)l * NQKV * DM, bqkv + l * NQKV, qkvb);
        k_attn2<<<dim3(TSEQ / QT, 4, NBATCH), 256, 0, stream>>>(qkvb, obf);
        k_gemm_ln<DM><<<NTOK / 32, 128, 0, stream>>>(
            obf, wo + (size_t)l * DM * DM, bo + l * DM, ln1g + l * DM, ln1b + l * DM, h, hbf);
        k_ff_fused<<<NTOK / 32, 128, 0, stream>>>(
            hbf, w1 + (size_t)l * DFF * DM, bff1 + l * DFF,
            w2 + (size_t)l * DM * DFF, bff2 + l * DM,
            ln2g + l * DM, ln2b + l * DM, h, hbf);
    }
    k_head<<<NTOK / 256, 256, 0, stream>>>(h, Whead, bhead, out);
}